// Round 7
// baseline (312.144 us; speedup 1.0000x reference)
//
#include <hip/hip_runtime.h>
#include <hip/hip_bf16.h>

// CTC loss, FUSED single kernel: one block per batch element, 512 thr = 8 waves.
//   Phase A (all 8 waves): gather p[b][t][ext_r]+EPS -> bf16, packed 8 steps
//     per uint4, into LDS sG[chunk][r] (r<64: label rows, r==64: blank).
//     Coalesced float2 row loads + ds_bpermute lane crossbar (no staging).
//   Phase B (wave 0 only, after one barrier): alpha recursion in LINEAR f64
//     domain (range 1e+-308), DPP wave_shr neighbor term, exact power-of-2
//     renorm every 32 steps via integer exponent max-reduce.
// No workspace, no intermediate global traffic, single launch.

typedef unsigned int u32;
typedef unsigned long long u64;

constexpr int B = 512, T = 512, C = 128, L = 64;
constexpr int NCHUNK = T / 8;    // 64 chunks of 8 timesteps
constexpr float EPS = 1e-7f;
constexpr float LN2 = 0.69314718055994530942f;

__device__ __forceinline__ u32 rne16(u32 b) {       // f32 bits -> bf16 (RNE)
    return (b + 0x7FFFu + ((b >> 16) & 1u)) >> 16;
}
__device__ __forceinline__ double dpp64_shr1(double x) {
    // lane i <- lane i-1 ; lane 0 -> 0.0
    union { double d; u32 u[2]; } in, out;
    in.d = x;
    out.u[0] = (u32)__builtin_amdgcn_update_dpp(0, (int)in.u[0], 0x138, 0xF, 0xF, false);
    out.u[1] = (u32)__builtin_amdgcn_update_dpp(0, (int)in.u[1], 0x138, 0xF, 0xF, false);
    return out.d;
}
template <int CTRL>
__device__ __forceinline__ u32 dpp_maxu_step(u32 m) {
    u32 t = (u32)__builtin_amdgcn_update_dpp(0, (int)m, CTRL, 0xF, 0xF, false);
    return m > t ? m : t;
}
__device__ __forceinline__ double exp2_exact(int e) {  // 2^e
    union { double d; u64 u; } s; s.u = (u64)(1023 + e) << 52; return s.d;
}

struct Bank { uint4 own[4]; uint4 blk[4]; };

__global__ __launch_bounds__(512, 4)   // <=128 VGPR -> 2 blocks/CU (LDS-capped)
void ctc_fused(const int* __restrict__ y_true,
               const float* __restrict__ y_pred,
               float* __restrict__ out) {
    __shared__ uint4 sG[NCHUNK * 65];   // 66560 B: [chunk][r], r=64 is blank

    const int b    = blockIdx.x;
    const int wave = threadIdx.x >> 6;
    const int lane = threadIdx.x & 63;

    const int lab  = y_true[b * L + lane];   // label of row r=lane
    const int perm = (lab >> 1) << 2;        // bpermute byte address
    const bool sel_hi = (lab & 1);

    // ---------------- Phase A: gather into LDS ----------------
    {
        const float2* __restrict__ base =
            (const float2*)(y_pred + (size_t)b * T * C) + lane;  // lane's 2 classes
        const int c0 = wave * 8;             // 8 chunks per wave

        float2 buf[2][8];
#pragma unroll
        for (int j = 0; j < 8; ++j) buf[0][j] = base[(c0 * 8 + j) * 64];

#pragma unroll
        for (int i = 0; i < 8; ++i) {
            const int c = c0 + i;
            if (i + 1 < 8) {
#pragma unroll
                for (int j = 0; j < 8; ++j)
                    buf[(i + 1) & 1][j] = base[((c + 1) * 8 + j) * 64];
            }
            const float2* row = buf[i & 1];

            u32 gl[8], gb[8];
#pragma unroll
            for (int j = 0; j < 8; ++j) {
                const int vx = __builtin_amdgcn_ds_bpermute(perm, __float_as_int(row[j].x));
                const int vy = __builtin_amdgcn_ds_bpermute(perm, __float_as_int(row[j].y));
                gl[j] = __float_as_uint(__int_as_float(sel_hi ? vy : vx) + EPS);
                gb[j] = __float_as_uint(__shfl(row[j].y, 63) + EPS);   // class 127
            }
            u32 wl[4], wb[4];
#pragma unroll
            for (int q = 0; q < 4; ++q) {
                wl[q] = rne16(gl[2 * q]) | (rne16(gl[2 * q + 1]) << 16);
                wb[q] = rne16(gb[2 * q]) | (rne16(gb[2 * q + 1]) << 16);
            }
            sG[c * 65 + lane] = make_uint4(wl[0], wl[1], wl[2], wl[3]);
            if (lane == 0)
                sG[c * 65 + 64] = make_uint4(wb[0], wb[1], wb[2], wb[3]);
        }
    }
    __syncthreads();
    if (threadIdx.x >= 64) return;           // waves 1-7 done

    // ---------------- Phase B: f64 linear-domain scan (wave 0) ----------------
    const int lab_prev = __shfl_up(lab, 1);
    const bool allow1 = (lane >= 1) && (lab != lab_prev);

    auto load_bank = [&](Bank& bk, int c0) {
#pragma unroll
        for (int c = 0; c < 4; ++c) {
            bk.own[c] = sG[(c0 + c) * 65 + lane];
            bk.blk[c] = sG[(c0 + c) * 65 + 64];
        }
    };

    // Virtual pre-state: step t=0 of the uniform body produces the true init.
    double d0 = (lane == 0) ? 1.0 : 0.0;   // alpha[2l]
    double d1 = 0.0;                       // alpha[2l+1]
    double d2 = 0.0;                       // alpha[128] (real on lane 63)
    int Ce = 0;                            // log2 scale: alpha_true = d * 2^Ce

    auto consume_bank = [&](const Bank& bk) {
#pragma unroll
        for (int c = 0; c < 4; ++c) {
            const u32* ow = (const u32*)&bk.own[c];
            const u32* bw = (const u32*)&bk.blk[c];
#pragma unroll
            for (int j = 0; j < 8; ++j) {
                const u32 wo = ow[j >> 1], wb = bw[j >> 1];
                const float fl = __uint_as_float((j & 1) ? (wo & 0xFFFF0000u) : (wo << 16));
                const float fb = __uint_as_float((j & 1) ? (wb & 0xFFFF0000u) : (wb << 16));
                const double Pl = (double)fl, Pb = (double)fb;
                const double p0  = dpp64_shr1(d1);     // alpha[2l-1]
                const double s01 = d0 + d1;            // independent of p0
                const double sel = allow1 ? p0 : 0.0;
                const double nd0 = (d0 + p0) * Pb;
                const double nd2 = (d2 + d1) * Pb;
                const double nd1 = (s01 + sel) * Pl;
                d0 = nd0; d1 = nd1; d2 = nd2;
            }
        }
    };

    auto renorm = [&]() {
        u32 h0 = (u32)__double2hiint(d0);
        u32 h1 = (u32)__double2hiint(d1);
        u32 m = h0 > h1 ? h0 : h1;
        m = dpp_maxu_step<0x111>(m);     // row_shr:1
        m = dpp_maxu_step<0x112>(m);     // row_shr:2
        m = dpp_maxu_step<0x114>(m);     // row_shr:4
        m = dpp_maxu_step<0x118>(m);     // row_shr:8
        m = dpp_maxu_step<0x142>(m);     // row_bcast:15
        m = dpp_maxu_step<0x143>(m);     // row_bcast:31 -> lane 63 has wave max
        const u32 M = (u32)__builtin_amdgcn_readlane((int)m, 63);
        const int e = (int)((M >> 20) & 0x7FFu) - 1023;
        const double s = exp2_exact(-e);
        d0 *= s; d1 *= s; d2 *= s;
        Ce += e;
    };

    Bank A, Bk;
    load_bank(A, 0);
    load_bank(Bk, 4);

#pragma unroll 1
    for (int k = 0; k < 16; k += 2) {    // 16 banks x 32 steps = 512 steps
        consume_bank(A);
        if (k + 2 < 16) load_bank(A, (k + 2) * 4);
        renorm();
        consume_bank(Bk);
        if (k + 3 < 16) load_bank(Bk, (k + 3) * 4);
        renorm();
    }

    if (lane == 63) {
        const double sum = d1 + d2;                   // alpha[127]+alpha[128]
        const int ee = ((__double2hiint(sum) >> 20) & 0x7FF) - 1023;
        const float mant = (float)(sum * exp2_exact(-ee));   // in [1,2)
        out[b] = -((float)(Ce + ee) + __log2f(mant)) * LN2;
    }
}

extern "C" void kernel_launch(void* const* d_in, const int* in_sizes, int n_in,
                              void* d_out, int out_size, void* d_ws, size_t ws_size,
                              hipStream_t stream) {
    const int*   y_true = (const int*)d_in[0];
    const float* y_pred = (const float*)d_in[1];
    float*       out    = (float*)d_out;
    ctc_fused<<<dim3(B), dim3(512), 0, stream>>>(y_true, y_pred, out);
}

// Round 8
// 206.315 us; speedup vs baseline: 1.5129x; 1.5129x over previous
//
#include <hip/hip_runtime.h>
#include <hip/hip_bf16.h>

// CTC loss, FUSED single kernel: one block per batch element, 512 thr = 8 waves.
//   Phase A (all 8 waves): gather p[b][t][ext_r]+EPS -> bf16, packed 8 steps
//     per uint4, into LDS sG[chunk][r] (r<64: label rows, r==64: blank).
//     Coalesced float2 row loads + ds_bpermute lane crossbar.
//   Phase B (wave 0 only, after one barrier): alpha recursion in LINEAR f64
//     domain, DPP wave_shr neighbor term, exact power-of-2 renorm every 32
//     steps via integer exponent max-reduce. 4-slot LDS prefetch (distance 4
//     chunks ~ 640 cyc >> 120 cyc LDS latency).
// R7 lesson: __launch_bounds__(512,4) capped VGPR at 64 -> phase-B prefetch
// banks spilled to scratch (WRITE_SIZE 203MB, 713 cyc/step). Occupancy is
// LDS-capped at 2 blocks/CU anyway, so NO min-waves clause here.

typedef unsigned int u32;
typedef unsigned long long u64;

constexpr int B = 512, T = 512, C = 128, L = 64;
constexpr int NCHUNK = T / 8;    // 64 chunks of 8 timesteps
constexpr float EPS = 1e-7f;
constexpr float LN2 = 0.69314718055994530942f;

__device__ __forceinline__ u32 rne16(u32 b) {       // f32 bits -> bf16 (RNE)
    return (b + 0x7FFFu + ((b >> 16) & 1u)) >> 16;
}
__device__ __forceinline__ double dpp64_shr1(double x) {
    // lane i <- lane i-1 ; lane 0 -> 0.0
    union { double d; u32 u[2]; } in, out;
    in.d = x;
    out.u[0] = (u32)__builtin_amdgcn_update_dpp(0, (int)in.u[0], 0x138, 0xF, 0xF, false);
    out.u[1] = (u32)__builtin_amdgcn_update_dpp(0, (int)in.u[1], 0x138, 0xF, 0xF, false);
    return out.d;
}
template <int CTRL>
__device__ __forceinline__ u32 dpp_maxu_step(u32 m) {
    u32 t = (u32)__builtin_amdgcn_update_dpp(0, (int)m, CTRL, 0xF, 0xF, false);
    return m > t ? m : t;
}
__device__ __forceinline__ double exp2_exact(int e) {  // 2^e
    union { double d; u64 u; } s; s.u = (u64)(1023 + e) << 52; return s.d;
}

__global__ __launch_bounds__(512)
void ctc_fused(const int* __restrict__ y_true,
               const float* __restrict__ y_pred,
               float* __restrict__ out) {
    __shared__ uint4 sG[NCHUNK * 65];   // 66560 B: [chunk][r], r=64 is blank

    const int b    = blockIdx.x;
    const int wave = threadIdx.x >> 6;
    const int lane = threadIdx.x & 63;

    const int lab  = y_true[b * L + lane];   // label of row r=lane
    const int perm = (lab >> 1) << 2;        // bpermute byte address
    const bool sel_hi = (lab & 1);

    // ---------------- Phase A: gather into LDS ----------------
    {
        const float2* __restrict__ base =
            (const float2*)(y_pred + (size_t)b * T * C) + lane;  // lane's 2 classes
        const int c0 = wave * 8;             // 8 chunks per wave

        float2 buf[2][8];
#pragma unroll
        for (int j = 0; j < 8; ++j) buf[0][j] = base[(c0 * 8 + j) * 64];

#pragma unroll
        for (int i = 0; i < 8; ++i) {
            const int c = c0 + i;
            if (i + 1 < 8) {
#pragma unroll
                for (int j = 0; j < 8; ++j)
                    buf[(i + 1) & 1][j] = base[((c + 1) * 8 + j) * 64];
            }
            const float2* row = buf[i & 1];

            u32 gl[8], gb[8];
#pragma unroll
            for (int j = 0; j < 8; ++j) {
                const int vx = __builtin_amdgcn_ds_bpermute(perm, __float_as_int(row[j].x));
                const int vy = __builtin_amdgcn_ds_bpermute(perm, __float_as_int(row[j].y));
                gl[j] = __float_as_uint(__int_as_float(sel_hi ? vy : vx) + EPS);
                gb[j] = __float_as_uint(__shfl(row[j].y, 63) + EPS);   // class 127
            }
            u32 wl[4], wb[4];
#pragma unroll
            for (int q = 0; q < 4; ++q) {
                wl[q] = rne16(gl[2 * q]) | (rne16(gl[2 * q + 1]) << 16);
                wb[q] = rne16(gb[2 * q]) | (rne16(gb[2 * q + 1]) << 16);
            }
            sG[c * 65 + lane] = make_uint4(wl[0], wl[1], wl[2], wl[3]);
            if (lane == 0)
                sG[c * 65 + 64] = make_uint4(wb[0], wb[1], wb[2], wb[3]);
        }
    }
    __syncthreads();
    if (threadIdx.x >= 64) return;           // waves 1-7 done

    // ---------------- Phase B: f64 linear-domain scan (wave 0) ----------------
    const int lab_prev = __shfl_up(lab, 1);
    const bool allow1 = (lane >= 1) && (lab != lab_prev);

    // 4-slot rotating LDS prefetch (distance 4 chunks).
    uint4 so[4], sb[4];
#pragma unroll
    for (int c = 0; c < 4; ++c) {
        so[c] = sG[c * 65 + lane];
        sb[c] = sG[c * 65 + 64];
    }

    // Virtual pre-state: step t=0 of the uniform body produces the true init.
    double d0 = (lane == 0) ? 1.0 : 0.0;   // alpha[2l]
    double d1 = 0.0;                       // alpha[2l+1]
    double d2 = 0.0;                       // alpha[128] (real on lane 63)
    int Ce = 0;                            // log2 scale: alpha_true = d * 2^Ce

#pragma unroll 4
    for (int c = 0; c < NCHUNK; ++c) {
        const int slot = c & 3;
        const uint4 uo = so[slot];
        const uint4 ub = sb[slot];
        const int nc = c + 4;
        if (nc < NCHUNK) {                  // wave-uniform
            so[slot] = sG[nc * 65 + lane];
            sb[slot] = sG[nc * 65 + 64];
        }

        const u32* ow = (const u32*)&uo;
        const u32* bw = (const u32*)&ub;
#pragma unroll
        for (int j = 0; j < 8; ++j) {
            const u32 wo = ow[j >> 1], wb = bw[j >> 1];
            const float fl = __uint_as_float((j & 1) ? (wo & 0xFFFF0000u) : (wo << 16));
            const float fb = __uint_as_float((j & 1) ? (wb & 0xFFFF0000u) : (wb << 16));
            const double Pl = (double)fl, Pb = (double)fb;
            const double p0  = dpp64_shr1(d1);     // alpha[2l-1]
            const double s01 = d0 + d1;            // independent of p0
            const double sel = allow1 ? p0 : 0.0;
            const double nd0 = (d0 + p0) * Pb;
            const double nd2 = (d2 + d1) * Pb;
            const double nd1 = (s01 + sel) * Pl;
            d0 = nd0; d1 = nd1; d2 = nd2;
        }

        if ((c & 3) == 3) {                 // renorm every 32 steps
            u32 h0 = (u32)__double2hiint(d0);
            u32 h1 = (u32)__double2hiint(d1);
            u32 m = h0 > h1 ? h0 : h1;
            m = dpp_maxu_step<0x111>(m);     // row_shr:1
            m = dpp_maxu_step<0x112>(m);     // row_shr:2
            m = dpp_maxu_step<0x114>(m);     // row_shr:4
            m = dpp_maxu_step<0x118>(m);     // row_shr:8
            m = dpp_maxu_step<0x142>(m);     // row_bcast:15
            m = dpp_maxu_step<0x143>(m);     // row_bcast:31 -> lane 63 has max
            const u32 M = (u32)__builtin_amdgcn_readlane((int)m, 63);
            const int e = (int)((M >> 20) & 0x7FFu) - 1023;
            const double s = exp2_exact(-e);
            d0 *= s; d1 *= s; d2 *= s;
            Ce += e;
        }
    }

    if (lane == 63) {
        const double sum = d1 + d2;                   // alpha[127]+alpha[128]
        const int ee = ((__double2hiint(sum) >> 20) & 0x7FF) - 1023;
        const float mant = (float)(sum * exp2_exact(-ee));   // in [1,2)
        out[b] = -((float)(Ce + ee) + __log2f(mant)) * LN2;
    }
}

extern "C" void kernel_launch(void* const* d_in, const int* in_sizes, int n_in,
                              void* d_out, int out_size, void* d_ws, size_t ws_size,
                              hipStream_t stream) {
    const int*   y_true = (const int*)d_in[0];
    const float* y_pred = (const float*)d_in[1];
    float*       out    = (float*)d_out;
    ctc_fused<<<dim3(B), dim3(512), 0, stream>>>(y_true, y_pred, out);
}

// Round 9
// 204.101 us; speedup vs baseline: 1.5294x; 1.0108x over previous
//
#include <hip/hip_runtime.h>
#include <hip/hip_bf16.h>

// CTC loss, FUSED single kernel: one block per batch element, 512 thr = 8 waves.
//   Phase A (all 8 waves): gather p[b][t][ext_r]+EPS -> bf16, packed 8 steps
//     per uint4, into LDS sG[chunk][r] (r<64: label rows, r==64: blank).
//     NONTEMPORAL coalesced u64 row loads (y_pred is read exactly once and the
//     harness leaves L3 full of dirty poison lines -> allocating reads pay a
//     ~1:1 writeback tax; nt loads dodge it) + ds_bpermute lane crossbar.
//   Phase B (wave 0 only, after one barrier): alpha recursion in LINEAR f64
//     domain, DPP wave_shr neighbor term, exact power-of-2 renorm every 32
//     steps via integer exponent max-reduce. 4-slot LDS prefetch.
// R7 lesson: NO min-waves clause (VGPR cap 64 spilled phase-B banks: 203 MB
// scratch traffic). Occupancy is LDS-capped at 2 blocks/CU regardless.

typedef unsigned int u32;
typedef unsigned long long u64;

constexpr int B = 512, T = 512, C = 128, L = 64;
constexpr int NCHUNK = T / 8;    // 64 chunks of 8 timesteps
constexpr float EPS = 1e-7f;
constexpr float LN2 = 0.69314718055994530942f;

__device__ __forceinline__ u32 rne16(u32 b) {       // f32 bits -> bf16 (RNE)
    return (b + 0x7FFFu + ((b >> 16) & 1u)) >> 16;
}
__device__ __forceinline__ double dpp64_shr1(double x) {
    // lane i <- lane i-1 ; lane 0 -> 0.0
    union { double d; u32 u[2]; } in, out;
    in.d = x;
    out.u[0] = (u32)__builtin_amdgcn_update_dpp(0, (int)in.u[0], 0x138, 0xF, 0xF, false);
    out.u[1] = (u32)__builtin_amdgcn_update_dpp(0, (int)in.u[1], 0x138, 0xF, 0xF, false);
    return out.d;
}
template <int CTRL>
__device__ __forceinline__ u32 dpp_maxu_step(u32 m) {
    u32 t = (u32)__builtin_amdgcn_update_dpp(0, (int)m, CTRL, 0xF, 0xF, false);
    return m > t ? m : t;
}
__device__ __forceinline__ double exp2_exact(int e) {  // 2^e
    union { double d; u64 u; } s; s.u = (u64)(1023 + e) << 52; return s.d;
}

__global__ __launch_bounds__(512)
void ctc_fused(const int* __restrict__ y_true,
               const float* __restrict__ y_pred,
               float* __restrict__ out) {
    __shared__ uint4 sG[NCHUNK * 65];   // 66560 B: [chunk][r], r=64 is blank

    const int b    = blockIdx.x;
    const int wave = threadIdx.x >> 6;
    const int lane = threadIdx.x & 63;

    const int lab  = y_true[b * L + lane];   // label of row r=lane
    const int perm = (lab >> 1) << 2;        // bpermute byte address
    const bool sel_hi = (lab & 1);

    // ---------------- Phase A: gather into LDS ----------------
    {
        // lane owns classes 2*lane, 2*lane+1 of each t-row (u64 = 2 floats)
        const u64* __restrict__ base =
            (const u64*)(y_pred + (size_t)b * T * C) + lane;
        const int c0 = wave * 8;             // 8 chunks per wave

        u64 buf[2][8];
#pragma unroll
        for (int j = 0; j < 8; ++j)
            buf[0][j] = __builtin_nontemporal_load(base + (c0 * 8 + j) * 64);

#pragma unroll
        for (int i = 0; i < 8; ++i) {
            const int c = c0 + i;
            if (i + 1 < 8) {
#pragma unroll
                for (int j = 0; j < 8; ++j)
                    buf[(i + 1) & 1][j] =
                        __builtin_nontemporal_load(base + ((c + 1) * 8 + j) * 64);
            }
            const u64* row = buf[i & 1];

            u32 gl[8], gb[8];
#pragma unroll
            for (int j = 0; j < 8; ++j) {
                const int lo = (int)(u32)row[j];
                const int hi = (int)(u32)(row[j] >> 32);
                const int vx = __builtin_amdgcn_ds_bpermute(perm, lo);
                const int vy = __builtin_amdgcn_ds_bpermute(perm, hi);
                gl[j] = __float_as_uint(__int_as_float(sel_hi ? vy : vx) + EPS);
                // class 127 = hi dword of lane 63 (wave-uniform broadcast)
                gb[j] = __float_as_uint(__int_as_float(__shfl(hi, 63)) + EPS);
            }
            u32 wl[4], wb[4];
#pragma unroll
            for (int q = 0; q < 4; ++q) {
                wl[q] = rne16(gl[2 * q]) | (rne16(gl[2 * q + 1]) << 16);
                wb[q] = rne16(gb[2 * q]) | (rne16(gb[2 * q + 1]) << 16);
            }
            sG[c * 65 + lane] = make_uint4(wl[0], wl[1], wl[2], wl[3]);
            if (lane == 0)
                sG[c * 65 + 64] = make_uint4(wb[0], wb[1], wb[2], wb[3]);
        }
    }
    __syncthreads();
    if (threadIdx.x >= 64) return;           // waves 1-7 done

    // ---------------- Phase B: f64 linear-domain scan (wave 0) ----------------
    const int lab_prev = __shfl_up(lab, 1);
    const bool allow1 = (lane >= 1) && (lab != lab_prev);

    // 4-slot rotating LDS prefetch (distance 4 chunks).
    uint4 so[4], sb[4];
#pragma unroll
    for (int c = 0; c < 4; ++c) {
        so[c] = sG[c * 65 + lane];
        sb[c] = sG[c * 65 + 64];
    }

    // Virtual pre-state: step t=0 of the uniform body produces the true init.
    double d0 = (lane == 0) ? 1.0 : 0.0;   // alpha[2l]
    double d1 = 0.0;                       // alpha[2l+1]
    double d2 = 0.0;                       // alpha[128] (real on lane 63)
    int Ce = 0;                            // log2 scale: alpha_true = d * 2^Ce

#pragma unroll 4
    for (int c = 0; c < NCHUNK; ++c) {
        const int slot = c & 3;
        const uint4 uo = so[slot];
        const uint4 ub = sb[slot];
        const int nc = c + 4;
        if (nc < NCHUNK) {                  // wave-uniform
            so[slot] = sG[nc * 65 + lane];
            sb[slot] = sG[nc * 65 + 64];
        }

        const u32* ow = (const u32*)&uo;
        const u32* bw = (const u32*)&ub;
#pragma unroll
        for (int j = 0; j < 8; ++j) {
            const u32 wo = ow[j >> 1], wb = bw[j >> 1];
            const float fl = __uint_as_float((j & 1) ? (wo & 0xFFFF0000u) : (wo << 16));
            const float fb = __uint_as_float((j & 1) ? (wb & 0xFFFF0000u) : (wb << 16));
            const double Pl = (double)fl, Pb = (double)fb;
            const double p0  = dpp64_shr1(d1);     // alpha[2l-1]
            const double s01 = d0 + d1;            // independent of p0
            const double sel = allow1 ? p0 : 0.0;
            const double nd0 = (d0 + p0) * Pb;
            const double nd2 = (d2 + d1) * Pb;
            const double nd1 = (s01 + sel) * Pl;
            d0 = nd0; d1 = nd1; d2 = nd2;
        }

        if ((c & 3) == 3) {                 // renorm every 32 steps
            u32 h0 = (u32)__double2hiint(d0);
            u32 h1 = (u32)__double2hiint(d1);
            u32 m = h0 > h1 ? h0 : h1;
            m = dpp_maxu_step<0x111>(m);     // row_shr:1
            m = dpp_maxu_step<0x112>(m);     // row_shr:2
            m = dpp_maxu_step<0x114>(m);     // row_shr:4
            m = dpp_maxu_step<0x118>(m);     // row_shr:8
            m = dpp_maxu_step<0x142>(m);     // row_bcast:15
            m = dpp_maxu_step<0x143>(m);     // row_bcast:31 -> lane 63 has max
            const u32 M = (u32)__builtin_amdgcn_readlane((int)m, 63);
            const int e = (int)((M >> 20) & 0x7FFu) - 1023;
            const double s = exp2_exact(-e);
            d0 *= s; d1 *= s; d2 *= s;
            Ce += e;
        }
    }

    if (lane == 63) {
        const double sum = d1 + d2;                   // alpha[127]+alpha[128]
        const int ee = ((__double2hiint(sum) >> 20) & 0x7FF) - 1023;
        const float mant = (float)(sum * exp2_exact(-ee));   // in [1,2)
        out[b] = -((float)(Ce + ee) + __log2f(mant)) * LN2;
    }
}

extern "C" void kernel_launch(void* const* d_in, const int* in_sizes, int n_in,
                              void* d_out, int out_size, void* d_ws, size_t ws_size,
                              hipStream_t stream) {
    const int*   y_true = (const int*)d_in[0];
    const float* y_pred = (const float*)d_in[1];
    float*       out    = (float*)d_out;
    ctc_fused<<<dim3(B), dim3(512), 0, stream>>>(y_true, y_pred, out);
}